// Round 1
// baseline (694.751 us; speedup 1.0000x reference)
//
#include <hip/hip_runtime.h>

// Linear_6983616824492: e3nn-style irrep linear, B=50000, blocks (mul,d):
// (256,1)@off0, (256,3)@off256, (128,5)@off1024, row = 1664 fp32.
// Strategy: bf16 MFMA (16x16x32), memory-bound streaming kernel.
//  - prep kernel: W -> bf16, pre-swizzled into B-fragment order in d_ws
//  - main kernel: 4-wave WG per 16-row batch tile per block; A-frags loaded
//    directly from global as contiguous float4s, cvt->bf16 in registers
//    (stride-d interleave resolved at compile time); full-K register accum;
//    epilogue scales by path weight. No LDS, no __syncthreads.

typedef __attribute__((ext_vector_type(8))) short short8;   // 8 bf16 (4 VGPRs)
typedef __attribute__((ext_vector_type(4))) float f32x4;    // MFMA C/D frag

#define NBATCH 50000
#define NTOTAL 1664

__device__ __forceinline__ unsigned short f2bf(float f) {
    union { float f; unsigned u; } v; v.f = f;
    unsigned r = v.u + 0x7fffu + ((v.u >> 16) & 1u);  // round-nearest-even
    return (unsigned short)(r >> 16);
}

// ---------------- prep: swizzled bf16 B operands into workspace -------------
// Per block, flat element e: j = e&7, lane = (e>>3)&63, qt = e>>9,
// t = qt % NT, q = qt / NT.  value = bf16(W[(q*32 + (lane>>4)*8 + j)*N
//                                          + t*16 + (lane&15)])
// Main kernel then loads short8 at index (q*NT + t)*64 + lane  (16B/lane,
// 1KB contiguous per wave instruction, L2-resident: total 288KB).
__global__ void prep_kernel(const float* __restrict__ w0,
                            const float* __restrict__ w1,
                            const float* __restrict__ w2,
                            unsigned short* __restrict__ ws) {
    int e = blockIdx.x * blockDim.x + threadIdx.x;
    const float* W; int N, base;
    if (e < 65536)       { W = w0; N = 256; base = 0; }
    else if (e < 131072) { W = w1; N = 256; base = 65536;  e -= 65536; }
    else if (e < 147456) { W = w2; N = 128; base = 131072; e -= 131072; }
    else return;
    int j = e & 7;
    int lane = (e >> 3) & 63;
    int qt = e >> 9;
    int NT = N >> 4;
    int t = qt % NT;
    int q = qt / NT;
    int u = q * 32 + ((lane >> 4) << 3) + j;
    int w = t * 16 + (lane & 15);
    ws[base + e] = f2bf(W[u * N + w]);
}

// ---------------- main kernel ----------------------------------------------
// D = irrep dim, K = mul (contraction), NT = total 16-wide w-tiles,
// NTW = w-tiles per wave (NT/4), OFF = column offset of this block.
// MFMA 16x16x32_bf16 layouts (HW-verified per guide):
//   A: lane holds A[m=lane&15][k=(lane>>4)*8+j]
//   B: lane holds B[k=(lane>>4)*8+j][n=lane&15]
//   C/D: reg r holds C[row=(lane>>4)*4+r][col=lane&15]
template<int D, int K, int NT, int NTW, int OFF>
__device__ __forceinline__ void run_block(const float* __restrict__ x,
                                          float* __restrict__ out,
                                          const short8* __restrict__ bsw,
                                          float pw) {
    const int lane = threadIdx.x & 63;
    const int wave = threadIdx.x >> 6;
    const int bcol = lane & 15;   // A row (m) for loads, C col (n) for stores
    const int quad = lane >> 4;
    const int b0 = blockIdx.x << 4;

    // lane's A source row + base offset of its k-octet within a u-chunk
    const float* xrow = x + (size_t)(b0 + bcol) * NTOTAL + OFF + quad * 8 * D;

    f32x4 acc[NTW][D];
#pragma unroll
    for (int tt = 0; tt < NTW; ++tt)
#pragma unroll
        for (int i = 0; i < D; ++i)
            acc[tt][i] = (f32x4){0.f, 0.f, 0.f, 0.f};

    for (int q = 0; q < K / 32; ++q) {
        // lane reads 8*D consecutive floats = all D A-frags for this u-chunk
        const float4* xp = (const float4*)(xrow + q * 32 * D);
        float xs[8 * D];
#pragma unroll
        for (int m = 0; m < 2 * D; ++m)
            ((float4*)xs)[m] = xp[m];

        short8 af[D];
#pragma unroll
        for (int i = 0; i < D; ++i)
#pragma unroll
            for (int j = 0; j < 8; ++j)
                af[i][j] = (short)f2bf(xs[j * D + i]);

#pragma unroll
        for (int tt = 0; tt < NTW; ++tt) {
            const int t = wave * NTW + tt;
            short8 bf = bsw[(q * NT + t) * 64 + lane];
#pragma unroll
            for (int i = 0; i < D; ++i)
                acc[tt][i] = __builtin_amdgcn_mfma_f32_16x16x32_bf16(
                    af[i], bf, acc[tt][i], 0, 0, 0);
        }
    }

    // epilogue: y[b0+quad*4+r][OFF + (t*16+bcol)*D + i] = pw * acc
#pragma unroll
    for (int tt = 0; tt < NTW; ++tt) {
        const int wcol = (wave * NTW + tt) * 16 + bcol;
#pragma unroll
        for (int r = 0; r < 4; ++r) {
            float* op = out + (size_t)(b0 + quad * 4 + r) * NTOTAL + OFF
                        + wcol * D;
#pragma unroll
            for (int i = 0; i < D; ++i)
                op[i] = acc[tt][i][r] * pw;
        }
    }
}

__global__ __launch_bounds__(256, 3)
void linear_kernel(const float* __restrict__ x, float* __restrict__ out,
                   const unsigned short* __restrict__ ws) {
    const short8* bs0 = (const short8*)(ws);
    const short8* bs1 = (const short8*)(ws + 65536);
    const short8* bs2 = (const short8*)(ws + 131072);
    if (blockIdx.y == 0)
        run_block<1, 256, 16, 4, 0>(x, out, bs0, 0.0625f);
    else if (blockIdx.y == 1)
        run_block<3, 256, 16, 4, 256>(x, out, bs1, 0.0625f);
    else
        run_block<5, 128, 8, 2, 1024>(x, out, bs2, 0.08838834764831845f);
}

extern "C" void kernel_launch(void* const* d_in, const int* in_sizes, int n_in,
                              void* d_out, int out_size, void* d_ws,
                              size_t ws_size, hipStream_t stream) {
    const float* x  = (const float*)d_in[0];
    const float* w0 = (const float*)d_in[1];
    const float* w1 = (const float*)d_in[2];
    const float* w2 = (const float*)d_in[3];
    unsigned short* ws = (unsigned short*)d_ws;  // needs 294912 B

    prep_kernel<<<dim3(576), 256, 0, stream>>>(w0, w1, w2, ws);

    dim3 grid(NBATCH / 16, 3);  // 50000 = 16 * 3125 exactly
    linear_kernel<<<grid, 256, 0, stream>>>(x, (float*)d_out, ws);
}